// Round 1
// baseline (520.378 us; speedup 1.0000x reference)
//
#include <hip/hip_runtime.h>
#include <hip/hip_bf16.h>
#include <stdint.h>

// Problem dims (fixed by reference setup_inputs)
#define M_DIM 8192   // B*S = 4*2048
#define N_DIM 4096   // D_OUT
#define K_DIM 4096   // D_IN

typedef __hip_bfloat16 bf16;
typedef __attribute__((ext_vector_type(8))) short bf16x8;   // MFMA A/B frag (8 bf16 = 4 VGPRs)
typedef __attribute__((ext_vector_type(4))) float floatx4;  // MFMA C/D frag

typedef const uint32_t GQ __attribute__((address_space(1)));
typedef uint32_t LQ __attribute__((address_space(3)));

__device__ __forceinline__ uint2 pack_bf16x4(float4 v) {
  bf16 b0 = __float2bfloat16(v.x);
  bf16 b1 = __float2bfloat16(v.y);
  bf16 b2 = __float2bfloat16(v.z);
  bf16 b3 = __float2bfloat16(v.w);
  unsigned int lo = (unsigned int)*(unsigned short*)&b0 |
                    ((unsigned int)*(unsigned short*)&b1 << 16);
  unsigned int hi = (unsigned int)*(unsigned short*)&b2 |
                    ((unsigned int)*(unsigned short*)&b3 << 16);
  return make_uint2(lo, hi);
}

// -------------------------------------------------------------------------
// Kernel 1: fake-quant weight (INT2, per-128-group min/max) -> bf16.
// (unchanged — near BW roofline, not in top-5 dispatches)
// -------------------------------------------------------------------------
__global__ void quant_w_kernel(const float* __restrict__ w, bf16* __restrict__ wq) {
  const int t = blockIdx.x * blockDim.x + threadIdx.x;
  const int g = t >> 4;        // group id (128 contiguous elems)
  const int s = t & 15;        // sub-lane within group

  const float4* p = (const float4*)(w + (size_t)g * 128);
  float4 a = p[s];
  float4 b = p[s + 16];

  float mn = fminf(fminf(fminf(a.x, a.y), fminf(a.z, a.w)),
                   fminf(fminf(b.x, b.y), fminf(b.z, b.w)));
  float mx = fmaxf(fmaxf(fmaxf(a.x, a.y), fmaxf(a.z, a.w)),
                   fmaxf(fmaxf(b.x, b.y), fmaxf(b.z, b.w)));
#pragma unroll
  for (int off = 8; off >= 1; off >>= 1) {
    mn = fminf(mn, __shfl_xor(mn, off));
    mx = fmaxf(mx, __shfl_xor(mx, off));
  }
  const float rng = mx - mn;
  float4 oa, ob;
  if (rng < 1e-8f) {
    oa = a; ob = b;            // pass-through for near-constant groups
  } else {
    const float scale = rng / 3.0f;  // max_q = 3 for INT2
    float q0 = fminf(fmaxf(rintf((a.x - mn) / scale), 0.f), 3.f);
    float q1 = fminf(fmaxf(rintf((a.y - mn) / scale), 0.f), 3.f);
    float q2 = fminf(fmaxf(rintf((a.z - mn) / scale), 0.f), 3.f);
    float q3 = fminf(fmaxf(rintf((a.w - mn) / scale), 0.f), 3.f);
    float q4 = fminf(fmaxf(rintf((b.x - mn) / scale), 0.f), 3.f);
    float q5 = fminf(fmaxf(rintf((b.y - mn) / scale), 0.f), 3.f);
    float q6 = fminf(fmaxf(rintf((b.z - mn) / scale), 0.f), 3.f);
    float q7 = fminf(fmaxf(rintf((b.w - mn) / scale), 0.f), 3.f);
    oa = make_float4(q0 * scale + mn, q1 * scale + mn, q2 * scale + mn, q3 * scale + mn);
    ob = make_float4(q4 * scale + mn, q5 * scale + mn, q6 * scale + mn, q7 * scale + mn);
  }
  uint2* q = (uint2*)(wq + (size_t)g * 128);
  q[s]      = pack_bf16x4(oa);
  q[s + 16] = pack_bf16x4(ob);
}

// -------------------------------------------------------------------------
// Kernel 2: cast x fp32 -> bf16, 8 elems/thread (unchanged)
// -------------------------------------------------------------------------
__global__ void cast_x_kernel(const float* __restrict__ x, bf16* __restrict__ xb) {
  const size_t base = (size_t)blockIdx.x * 512;  // float4 units
  const int tid = threadIdx.x;
  const float4* p = (const float4*)x + base;
  float4 a = p[tid];
  float4 b = p[tid + 256];
  uint2* q = (uint2*)xb + base;
  q[tid]       = pack_bf16x4(a);
  q[tid + 256] = pack_bf16x4(b);
}

// -------------------------------------------------------------------------
// Kernel 3: C[M,N] = A[M,K] * Bw[N,K]^T + bias — 256x256 8-phase schedule.
//
// vs previous round (128x128, __syncthreads per K-step = vmcnt(0) drain,
// 1095 TF, MfmaUtil 52%): this is the m201-style counted-vmcnt pipeline.
//  - 8 waves (2M x 4N), per-wave 128x64 output = acc[8][4] 16x16 frags.
//  - LDS 128 KiB: double-buffered A(256x64) + B(256x64) bf16.
//  - Per K-tile: 4 phases, each {ds_read subtile; s_barrier; lgkmcnt(0);
//    setprio(1); 16 MFMA; setprio(0); s_barrier}. Snake quadrant order
//    (NloNhi x MloMhi) reuses A-frags across phase pairs -> 24 ds_read/tile.
//  - Staging: tile t+2 issued into buf[t&1] right after its last reader
//    phase; wait is s_waitcnt vmcnt(8) (= the 8 just-issued loads stay in
//    flight) — NEVER vmcnt(0) in the main loop. Raw s_barrier only; no
//    __syncthreads anywhere in the K-loop.
//  - XOR swizzle pair kept verbatim from the proven kernel (bank conflicts
//    measured 0): staging fetches logical chunk (l&7)^((l>>3)&7), frag
//    reads use physical chunk ((kk/8 + lane>>4) ^ (lane&7)).
//  - ds_read via inline asm (+ sched_barrier(0) after lgkmcnt per rule) so
//    the compiler can neither insert conservative vmcnt(0) drains nor hoist
//    MFMAs past the wait.
// -------------------------------------------------------------------------
#define BM 256
#define BN 256
#define BK 64
#define NT (K_DIM / BK)   // 64, even

#define MFMA_BF16 __builtin_amdgcn_mfma_f32_16x16x32_bf16

__device__ __forceinline__ bf16x8 lds_read_b128(const bf16* p) {
  bf16x8 r;
  asm volatile("ds_read_b128 %0, %1" : "=v"(r) : "v"((const LQ*)p));
  return r;
}

// Stage one K-tile (A 256x64 + B 256x64) via global_load_lds, 8 issues/thread.
__device__ __forceinline__ void stage_tile(const bf16* __restrict__ Ag,
                                           const bf16* __restrict__ Bg,
                                           bf16* sa, bf16* sb,
                                           int k0, int warp, int lane) {
  const int srow = warp * 8 + (lane >> 3);                 // 0..63 per round
  const int scol = ((lane & 7) ^ ((lane >> 3) & 7)) * 8;   // pre-swizzled source
#pragma unroll
  for (int j = 0; j < 4; ++j) {
    const bf16* g = Ag + (size_t)(j * 64 + srow) * K_DIM + (k0 + scol);
    bf16* l = sa + (j * 64 + warp * 8) * BK;  // wave-uniform LDS base
    __builtin_amdgcn_global_load_lds((GQ*)g, (LQ*)l, 16, 0, 0);
  }
#pragma unroll
  for (int j = 0; j < 4; ++j) {
    const bf16* g = Bg + (size_t)(j * 64 + srow) * K_DIM + (k0 + scol);
    bf16* l = sb + (j * 64 + warp * 8) * BK;
    __builtin_amdgcn_global_load_lds((GQ*)g, (LQ*)l, 16, 0, 0);
  }
}

#define PHASE_WAIT()                                    \
  __builtin_amdgcn_s_barrier();                         \
  __builtin_amdgcn_sched_barrier(0);                    \
  asm volatile("s_waitcnt lgkmcnt(0)" ::: "memory");    \
  __builtin_amdgcn_sched_barrier(0);                    \
  __builtin_amdgcn_s_setprio(1)

#define PHASE_CLOSE()                                   \
  __builtin_amdgcn_s_setprio(0);                        \
  __builtin_amdgcn_sched_barrier(0);                    \
  __builtin_amdgcn_s_barrier();                         \
  __builtin_amdgcn_sched_barrier(0)

// 4 phases consuming one K-tile from (sa, sb). Ends with a barrier, so the
// caller may immediately overwrite (sa, sb) with new staging issues.
__device__ __forceinline__ void do_ktile(const bf16* sa, const bf16* sb,
                                         floatx4 (&acc)[8][4],
                                         const int aBase, const int bBase,
                                         const int c0, const int c1) {
  bf16x8 af[4][2];   // 4 M-frags x 2 k-steps (reused: mi0-3 then mi4-7)
  bf16x8 bfr[2][2];  // 2 N-frags x 2 k-steps (reloaded per phase pair)

  // ---- phase 1: load A[0..3], B[0..1]; MFMA quadrant (Mlo, Nlo)
#pragma unroll
  for (int i = 0; i < 4; ++i) {
    af[i][0] = lds_read_b128(sa + aBase + i * 16 * BK + c0);
    af[i][1] = lds_read_b128(sa + aBase + i * 16 * BK + c1);
  }
#pragma unroll
  for (int j = 0; j < 2; ++j) {
    bfr[j][0] = lds_read_b128(sb + bBase + j * 16 * BK + c0);
    bfr[j][1] = lds_read_b128(sb + bBase + j * 16 * BK + c1);
  }
  PHASE_WAIT();
#pragma unroll
  for (int s = 0; s < 2; ++s)
#pragma unroll
    for (int i = 0; i < 4; ++i)
#pragma unroll
      for (int j = 0; j < 2; ++j)
        acc[i][j] = MFMA_BF16(af[i][s], bfr[j][s], acc[i][j], 0, 0, 0);
  PHASE_CLOSE();

  // ---- phase 2: load B[2..3]; MFMA quadrant (Mlo, Nhi) (reuse A[0..3])
#pragma unroll
  for (int j = 0; j < 2; ++j) {
    bfr[j][0] = lds_read_b128(sb + bBase + (2 + j) * 16 * BK + c0);
    bfr[j][1] = lds_read_b128(sb + bBase + (2 + j) * 16 * BK + c1);
  }
  PHASE_WAIT();
#pragma unroll
  for (int s = 0; s < 2; ++s)
#pragma unroll
    for (int i = 0; i < 4; ++i)
#pragma unroll
      for (int j = 0; j < 2; ++j)
        acc[i][2 + j] = MFMA_BF16(af[i][s], bfr[j][s], acc[i][2 + j], 0, 0, 0);
  PHASE_CLOSE();

  // ---- phase 3: load A[4..7]; MFMA quadrant (Mhi, Nhi) (reuse B[2..3])
#pragma unroll
  for (int i = 0; i < 4; ++i) {
    af[i][0] = lds_read_b128(sa + aBase + (4 + i) * 16 * BK + c0);
    af[i][1] = lds_read_b128(sa + aBase + (4 + i) * 16 * BK + c1);
  }
  PHASE_WAIT();
#pragma unroll
  for (int s = 0; s < 2; ++s)
#pragma unroll
    for (int i = 0; i < 4; ++i)
#pragma unroll
      for (int j = 0; j < 2; ++j)
        acc[4 + i][2 + j] = MFMA_BF16(af[i][s], bfr[j][s], acc[4 + i][2 + j], 0, 0, 0);
  PHASE_CLOSE();

  // ---- phase 4: re-load B[0..1]; MFMA quadrant (Mhi, Nlo) (reuse A[4..7])
#pragma unroll
  for (int j = 0; j < 2; ++j) {
    bfr[j][0] = lds_read_b128(sb + bBase + j * 16 * BK + c0);
    bfr[j][1] = lds_read_b128(sb + bBase + j * 16 * BK + c1);
  }
  PHASE_WAIT();
#pragma unroll
  for (int s = 0; s < 2; ++s)
#pragma unroll
    for (int i = 0; i < 4; ++i)
#pragma unroll
      for (int j = 0; j < 2; ++j)
        acc[4 + i][j] = MFMA_BF16(af[i][s], bfr[j][s], acc[4 + i][j], 0, 0, 0);
  PHASE_CLOSE();
}

__global__ __launch_bounds__(512, 2)
void gemm_bt_kernel(const bf16* __restrict__ A,   // [M,K] bf16
                    const bf16* __restrict__ Bw,  // [N,K] bf16
                    const float* __restrict__ bias,
                    float* __restrict__ C) {      // [M,N] fp32
  extern __shared__ bf16 smem[];                  // 128 KiB dynamic
  bf16* sA0 = smem;                  // [256][64]
  bf16* sB0 = smem + 1 * BM * BK;
  bf16* sA1 = smem + 2 * BM * BK;
  bf16* sB1 = smem + 3 * BM * BK;

  const int tid  = threadIdx.x;
  const int lane = tid & 63;
  const int warp = tid >> 6;   // 0..7
  const int wm   = warp >> 2;  // 0..1 (M dir, 128 rows each)
  const int wn   = warp & 3;   // 0..3 (N dir, 64 cols each)
  const int m0   = blockIdx.y * BM;
  const int n0   = blockIdx.x * BN;

  const bf16* Ag = A  + (size_t)m0 * K_DIM;
  const bf16* Bg = Bw + (size_t)n0 * K_DIM;

  floatx4 acc[8][4];
#pragma unroll
  for (int i = 0; i < 8; ++i)
#pragma unroll
    for (int j = 0; j < 4; ++j)
      acc[i][j] = (floatx4){0.f, 0.f, 0.f, 0.f};

  // Fragment read geometry (16x16x32): row = base + (lane&15), k-chunk =
  // kk/8 + (lane>>4); physical chunk = logical ^ (row&7) = logical ^ (lane&7).
  const int fr = lane & 15;
  const int fs = lane & 7;
  const int fc = lane >> 4;
  const int c0 = ((0 + fc) ^ fs) * 8;   // kk = 0
  const int c1 = ((4 + fc) ^ fs) * 8;   // kk = 32
  const int aBase = (wm * 128 + fr) * BK;
  const int bBase = (wn * 64 + fr) * BK;

  // Prologue: tiles 0,1 in flight; wait tile 0 only (counted).
  stage_tile(Ag, Bg, sA0, sB0, 0 * BK, warp, lane);
  stage_tile(Ag, Bg, sA1, sB1, 1 * BK, warp, lane);
  asm volatile("s_waitcnt vmcnt(8)" ::: "memory");
  __builtin_amdgcn_s_barrier();
  __builtin_amdgcn_sched_barrier(0);

#pragma unroll 1
  for (int tt = 0; tt < NT; tt += 2) {
    // ---- K-tile tt from buf0
    do_ktile(sA0, sB0, acc, aBase, bBase, c0, c1);
    if (tt + 2 < NT) {
      stage_tile(Ag, Bg, sA0, sB0, (tt + 2) * BK, warp, lane);
      asm volatile("s_waitcnt vmcnt(8)" ::: "memory");  // tile tt+1 landed
    } else {
      asm volatile("s_waitcnt vmcnt(0)" ::: "memory");  // epilogue drain
    }
    __builtin_amdgcn_s_barrier();
    __builtin_amdgcn_sched_barrier(0);

    // ---- K-tile tt+1 from buf1
    do_ktile(sA1, sB1, acc, aBase, bBase, c0, c1);
    if (tt + 3 < NT) {
      stage_tile(Ag, Bg, sA1, sB1, (tt + 3) * BK, warp, lane);
      asm volatile("s_waitcnt vmcnt(8)" ::: "memory");  // tile tt+2 landed
      __builtin_amdgcn_s_barrier();
      __builtin_amdgcn_sched_barrier(0);
    }
  }

  // Epilogue: C/D layout col=lane&15, row=(lane>>4)*4+reg
  const int cm = (lane >> 4) * 4;
  const int cn = lane & 15;
#pragma unroll
  for (int j = 0; j < 4; ++j) {
    const int col = n0 + wn * 64 + j * 16 + cn;
    const float bv = bias[col];
#pragma unroll
    for (int i = 0; i < 8; ++i) {
      const int rowb = m0 + wm * 128 + i * 16 + cm;
      float* outp = C + (size_t)rowb * N_DIM + col;
#pragma unroll
      for (int r = 0; r < 4; ++r)
        outp[(size_t)r * N_DIM] = acc[i][j][r] + bv;
    }
  }
}

// -------------------------------------------------------------------------
extern "C" void kernel_launch(void* const* d_in, const int* in_sizes, int n_in,
                              void* d_out, int out_size, void* d_ws, size_t ws_size,
                              hipStream_t stream) {
  const float* x      = (const float*)d_in[0];  // [4,2048,4096] fp32
  const float* weight = (const float*)d_in[1];  // [4096,4096] fp32
  const float* bias   = (const float*)d_in[2];  // [4096] fp32
  float* out          = (float*)d_out;          // [4,2048,4096] fp32

  // Workspace: wq bf16 [N,K] (32 MB) then xb bf16 [M,K] (64 MB)
  bf16* wq = (bf16*)d_ws;
  bf16* xb = (bf16*)((char*)d_ws + (size_t)N_DIM * K_DIM * sizeof(bf16));

  // 1) fake-quant + cast W
  {
    int threads = (N_DIM * K_DIM) / 8;
    quant_w_kernel<<<threads / 256, 256, 0, stream>>>(weight, wq);
  }
  // 2) cast X
  {
    int threads = (M_DIM * K_DIM) / 8;
    cast_x_kernel<<<threads / 256, 256, 0, stream>>>(x, xb);
  }
  // 3) GEMM: 256x256 tiles, 512 threads, 128 KiB dynamic LDS
  {
    constexpr int smem_bytes = 4 * BM * BK * (int)sizeof(bf16);  // 131072
    static bool attr_done = false;
    if (!attr_done) {
      (void)hipFuncSetAttribute((const void*)gemm_bt_kernel,
                                hipFuncAttributeMaxDynamicSharedMemorySize,
                                smem_bytes);
      attr_done = true;
    }
    dim3 grid(N_DIM / BN, M_DIM / BM);  // 16 x 32 = 512 blocks (2 per CU rounds)
    gemm_bt_kernel<<<grid, 512, smem_bytes, stream>>>(xb, wq, bias, out);
  }
}

// Round 2
// 485.986 us; speedup vs baseline: 1.0708x; 1.0708x over previous
//
#include <hip/hip_runtime.h>
#include <hip/hip_bf16.h>
#include <stdint.h>

// Problem dims (fixed by reference setup_inputs)
#define M_DIM 8192   // B*S = 4*2048
#define N_DIM 4096   // D_OUT
#define K_DIM 4096   // D_IN

typedef __hip_bfloat16 bf16;
typedef __attribute__((ext_vector_type(8))) short bf16x8;   // MFMA A/B frag (8 bf16 = 4 VGPRs)
typedef __attribute__((ext_vector_type(4))) float floatx4;  // MFMA C/D frag

typedef const uint32_t GQ __attribute__((address_space(1)));
typedef uint32_t LQ __attribute__((address_space(3)));

__device__ __forceinline__ uint2 pack_bf16x4(float4 v) {
  bf16 b0 = __float2bfloat16(v.x);
  bf16 b1 = __float2bfloat16(v.y);
  bf16 b2 = __float2bfloat16(v.z);
  bf16 b3 = __float2bfloat16(v.w);
  unsigned int lo = (unsigned int)*(unsigned short*)&b0 |
                    ((unsigned int)*(unsigned short*)&b1 << 16);
  unsigned int hi = (unsigned int)*(unsigned short*)&b2 |
                    ((unsigned int)*(unsigned short*)&b3 << 16);
  return make_uint2(lo, hi);
}

// -------------------------------------------------------------------------
// Kernel 1: fake-quant weight (INT2, per-128-group min/max) -> bf16.
// (unchanged)
// -------------------------------------------------------------------------
__global__ void quant_w_kernel(const float* __restrict__ w, bf16* __restrict__ wq) {
  const int t = blockIdx.x * blockDim.x + threadIdx.x;
  const int g = t >> 4;        // group id (128 contiguous elems)
  const int s = t & 15;        // sub-lane within group

  const float4* p = (const float4*)(w + (size_t)g * 128);
  float4 a = p[s];
  float4 b = p[s + 16];

  float mn = fminf(fminf(fminf(a.x, a.y), fminf(a.z, a.w)),
                   fminf(fminf(b.x, b.y), fminf(b.z, b.w)));
  float mx = fmaxf(fmaxf(fmaxf(a.x, a.y), fmaxf(a.z, a.w)),
                   fmaxf(fmaxf(b.x, b.y), fmaxf(b.z, b.w)));
#pragma unroll
  for (int off = 8; off >= 1; off >>= 1) {
    mn = fminf(mn, __shfl_xor(mn, off));
    mx = fmaxf(mx, __shfl_xor(mx, off));
  }
  const float rng = mx - mn;
  float4 oa, ob;
  if (rng < 1e-8f) {
    oa = a; ob = b;            // pass-through for near-constant groups
  } else {
    const float scale = rng / 3.0f;  // max_q = 3 for INT2
    float q0 = fminf(fmaxf(rintf((a.x - mn) / scale), 0.f), 3.f);
    float q1 = fminf(fmaxf(rintf((a.y - mn) / scale), 0.f), 3.f);
    float q2 = fminf(fmaxf(rintf((a.z - mn) / scale), 0.f), 3.f);
    float q3 = fminf(fmaxf(rintf((a.w - mn) / scale), 0.f), 3.f);
    float q4 = fminf(fmaxf(rintf((b.x - mn) / scale), 0.f), 3.f);
    float q5 = fminf(fmaxf(rintf((b.y - mn) / scale), 0.f), 3.f);
    float q6 = fminf(fmaxf(rintf((b.z - mn) / scale), 0.f), 3.f);
    float q7 = fminf(fmaxf(rintf((b.w - mn) / scale), 0.f), 3.f);
    oa = make_float4(q0 * scale + mn, q1 * scale + mn, q2 * scale + mn, q3 * scale + mn);
    ob = make_float4(q4 * scale + mn, q5 * scale + mn, q6 * scale + mn, q7 * scale + mn);
  }
  uint2* q = (uint2*)(wq + (size_t)g * 128);
  q[s]      = pack_bf16x4(oa);
  q[s + 16] = pack_bf16x4(ob);
}

// -------------------------------------------------------------------------
// Kernel 2: cast x fp32 -> bf16, 8 elems/thread (unchanged)
// -------------------------------------------------------------------------
__global__ void cast_x_kernel(const float* __restrict__ x, bf16* __restrict__ xb) {
  const size_t base = (size_t)blockIdx.x * 512;  // float4 units
  const int tid = threadIdx.x;
  const float4* p = (const float4*)x + base;
  float4 a = p[tid];
  float4 b = p[tid + 256];
  uint2* q = (uint2*)xb + base;
  q[tid]       = pack_bf16x4(a);
  q[tid + 256] = pack_bf16x4(b);
}

// -------------------------------------------------------------------------
// Kernel 3: 256x256 4-phase K-tile, spread half-tile staging, counted vmcnt.
//
// Round-1 post-mortem: lockstep phases serialized LDS service (2690 cyc/tile)
// against MFMA (2065 cyc/tile) -> MfmaUtil 41% ~= 2065/(2690+2065). Fixes:
//  - LDS halves match phase footprints: A half = output rows by bit6
//    ({0-63,128-191} / {64-127,192-255}), B half = rows by bit5. Each phase
//    reads exactly one A-half and/or one B-half -> halves free one phase
//    after their read phase, enabling staging DURING compute.
//  - Stage 1 half-tile (2 global_load_lds) per phase: q1: A-hi(u+1)->other
//    buf; q2: A-lo(u+2); q3: B-lo(u+2); q4: B-hi(u+2) (all into current buf,
//    each after its slot's last reader phase + barrier).
//  - One vmcnt(6) per tile (after q4's MFMA): 3 half-tiles stay in flight
//    across barriers. Never vmcnt(0) in the main loop.
//  - ONE barrier per phase (closing only): lgkmcnt(0)-before-MFMA already
//    guarantees each wave's ds_reads completed before it reaches the
//    closing barrier, so write-after-read hazards are covered; dropping the
//    opening barrier lets early-lgkm waves MFMA while LDS drains the rest.
//  - Reads balanced {12,4,8,0} = 24/tile (optimal; B-lo regs held q1->q4).
//  - XOR swizzle pair unchanged (proven 0 conflicts): stage fetches logical
//    chunk (l&7)^((l>>3)&7); reads use chunk ((kk/8+lane>>4)^(lane&7)).
// -------------------------------------------------------------------------
#define BM 256
#define BN 256
#define BK 64
#define NT (K_DIM / BK)   // 64, even
#define HALF 8192         // elems per half-tile (128 rows * 64 cols)

#define MFMA_BF16 __builtin_amdgcn_mfma_f32_16x16x32_bf16

__device__ __forceinline__ bf16x8 lds_read_b128(const bf16* p) {
  bf16x8 r;
  asm volatile("ds_read_b128 %0, %1" : "=v"(r) : "v"((const LQ*)p));
  return r;
}

// Stage one A half-tile (16 KB, 2 loads/thread). LDS rowIdx -> global tile
// row r = (idx&63) + hA*64 + (idx>>6)*128.
__device__ __forceinline__ void stage_A_half(const bf16* __restrict__ Ag,
                                             bf16* lds_half, int k0, int hA,
                                             int warp, int lane) {
  const int sub  = warp * 8 + (lane >> 3);                 // 0..63
  const int scol = ((lane & 7) ^ ((lane >> 3) & 7)) * 8;   // pre-swizzled src
#pragma unroll
  for (int i = 0; i < 2; ++i) {
    const int r = (sub & 63) + hA * 64 + i * 128;          // idx = i*64+sub
    const bf16* g = Ag + (size_t)r * K_DIM + (k0 + scol);
    bf16* l = lds_half + (i * 64 + warp * 8) * BK;         // wave-uniform
    __builtin_amdgcn_global_load_lds((GQ*)g, (LQ*)l, 16, 0, 0);
  }
}

// Stage one B half-tile. LDS rowIdx -> global tile row
// r = (idx&31) + hB*32 + (idx>>5)*64.
__device__ __forceinline__ void stage_B_half(const bf16* __restrict__ Bg,
                                             bf16* lds_half, int k0, int hB,
                                             int warp, int lane) {
  const int sub  = warp * 8 + (lane >> 3);
  const int scol = ((lane & 7) ^ ((lane >> 3) & 7)) * 8;
#pragma unroll
  for (int i = 0; i < 2; ++i) {
    const int idx = i * 64 + sub;
    const int r = (idx & 31) + hB * 32 + (idx >> 5) * 64;
    const bf16* g = Bg + (size_t)r * K_DIM + (k0 + scol);
    bf16* l = lds_half + (i * 64 + warp * 8) * BK;
    __builtin_amdgcn_global_load_lds((GQ*)g, (LQ*)l, 16, 0, 0);
  }
}

#define PHASE_MFMA_OPEN()                               \
  asm volatile("s_waitcnt lgkmcnt(0)" ::: "memory");    \
  __builtin_amdgcn_sched_barrier(0);                    \
  __builtin_amdgcn_s_setprio(1)

#define PHASE_CLOSE()                                   \
  __builtin_amdgcn_s_setprio(0);                        \
  __builtin_amdgcn_sched_barrier(0);                    \
  __builtin_amdgcn_s_barrier();                         \
  __builtin_amdgcn_sched_barrier(0)

// One K-tile = 4 phases: q1 (Mlo,Nlo), q2 (Mlo,Nhi), q3 (Mhi,Nhi), q4 (Mhi,Nlo).
// cA/cB: current buffers (also stage target for tile u+2); nA: other A buffer
// (stage target for A-hi(u+1)). k1 = (u+1)*BK, k2 = (u+2)*BK.
__device__ __forceinline__ void do_tile(const bf16* cA, const bf16* cB, bf16* nA,
                                        const bf16* __restrict__ Ag,
                                        const bf16* __restrict__ Bg,
                                        int k1, int k2, int g1, int g2,
                                        int warp, int lane,
                                        int aoff, int boff, int c0, int c1,
                                        floatx4 (&acc)[8][4]) {
  bf16x8 af[4][2];  // A frags (Mlo in q1-q2, reloaded as Mhi in q3-q4)
  bf16x8 bl[2][2];  // B-lo frags, held q1 -> q4
  bf16x8 bh[2][2];  // B-hi frags, held q2 -> q3

  // ---- q1: reads A-lo x8 + B-lo x4; stage A-hi(u+1); MFMA acc[0..3][0..1]
#pragma unroll
  for (int i = 0; i < 4; ++i) {
    af[i][0] = lds_read_b128(cA + aoff + i * 16 * BK + c0);
    af[i][1] = lds_read_b128(cA + aoff + i * 16 * BK + c1);
  }
#pragma unroll
  for (int j = 0; j < 2; ++j) {
    bl[j][0] = lds_read_b128(cB + boff + j * 16 * BK + c0);
    bl[j][1] = lds_read_b128(cB + boff + j * 16 * BK + c1);
  }
  if (g1) stage_A_half(Ag, nA + HALF, k1, 1, warp, lane);
  PHASE_MFMA_OPEN();
#pragma unroll
  for (int s = 0; s < 2; ++s)
#pragma unroll
    for (int i = 0; i < 4; ++i)
#pragma unroll
      for (int j = 0; j < 2; ++j)
        acc[i][j] = MFMA_BF16(af[i][s], bl[j][s], acc[i][j], 0, 0, 0);
  PHASE_CLOSE();

  // ---- q2: reads B-hi x4; stage A-lo(u+2); MFMA acc[0..3][2..3]
#pragma unroll
  for (int j = 0; j < 2; ++j) {
    bh[j][0] = lds_read_b128(cB + HALF + boff + j * 16 * BK + c0);
    bh[j][1] = lds_read_b128(cB + HALF + boff + j * 16 * BK + c1);
  }
  if (g2) stage_A_half(Ag, (bf16*)cA, k2, 0, warp, lane);
  PHASE_MFMA_OPEN();
#pragma unroll
  for (int s = 0; s < 2; ++s)
#pragma unroll
    for (int i = 0; i < 4; ++i)
#pragma unroll
      for (int j = 0; j < 2; ++j)
        acc[i][2 + j] = MFMA_BF16(af[i][s], bh[j][s], acc[i][2 + j], 0, 0, 0);
  PHASE_CLOSE();

  // ---- q3: reads A-hi x8 (overwrite af); stage B-lo(u+2); MFMA acc[4..7][2..3]
#pragma unroll
  for (int i = 0; i < 4; ++i) {
    af[i][0] = lds_read_b128(cA + HALF + aoff + i * 16 * BK + c0);
    af[i][1] = lds_read_b128(cA + HALF + aoff + i * 16 * BK + c1);
  }
  if (g2) stage_B_half(Bg, (bf16*)cB, k2, 0, warp, lane);
  PHASE_MFMA_OPEN();
#pragma unroll
  for (int s = 0; s < 2; ++s)
#pragma unroll
    for (int i = 0; i < 4; ++i)
#pragma unroll
      for (int j = 0; j < 2; ++j)
        acc[4 + i][2 + j] = MFMA_BF16(af[i][s], bh[j][s], acc[4 + i][2 + j], 0, 0, 0);
  PHASE_CLOSE();

  // ---- q4: no reads; stage B-hi(u+2); MFMA acc[4..7][0..1]; vmcnt; barrier
  if (g2) stage_B_half(Bg, (bf16*)cB + HALF, k2, 1, warp, lane);
  __builtin_amdgcn_s_setprio(1);
#pragma unroll
  for (int s = 0; s < 2; ++s)
#pragma unroll
    for (int i = 0; i < 4; ++i)
#pragma unroll
      for (int j = 0; j < 2; ++j)
        acc[4 + i][j] = MFMA_BF16(af[i][s], bl[j][s], acc[4 + i][j], 0, 0, 0);
  __builtin_amdgcn_s_setprio(0);
  __builtin_amdgcn_sched_barrier(0);
  if (g2) { asm volatile("s_waitcnt vmcnt(6)" ::: "memory"); }  // tile u+1 landed
  else    { asm volatile("s_waitcnt vmcnt(0)" ::: "memory"); }  // tail drain
  __builtin_amdgcn_s_barrier();
  __builtin_amdgcn_sched_barrier(0);
}

__global__ __launch_bounds__(512, 2)
void gemm_bt_kernel(const bf16* __restrict__ A,   // [M,K] bf16
                    const bf16* __restrict__ Bw,  // [N,K] bf16
                    const float* __restrict__ bias,
                    float* __restrict__ C) {      // [M,N] fp32
  extern __shared__ bf16 smem[];                  // 128 KiB dynamic
  bf16* sA0 = smem;                  // [2 halves][128][64]
  bf16* sB0 = smem + 16384;
  bf16* sA1 = smem + 32768;
  bf16* sB1 = smem + 49152;

  const int tid  = threadIdx.x;
  const int lane = tid & 63;
  const int warp = tid >> 6;   // 0..7
  const int wm   = warp >> 2;  // 0..1 (M dir, 128 rows each)
  const int wn   = warp & 3;   // 0..3 (N dir, 64 cols each)
  const int m0   = blockIdx.y * BM;
  const int n0   = blockIdx.x * BN;

  const bf16* Ag = A  + (size_t)m0 * K_DIM;
  const bf16* Bg = Bw + (size_t)n0 * K_DIM;

  floatx4 acc[8][4];
#pragma unroll
  for (int i = 0; i < 8; ++i)
#pragma unroll
    for (int j = 0; j < 4; ++j)
      acc[i][j] = (floatx4){0.f, 0.f, 0.f, 0.f};

  // Fragment read geometry (16x16x32): within-half rowIdx&7 = lane&7, so
  // physical chunk = (kk/8 + lane>>4) ^ (lane&7) — same proven swizzle.
  const int fr = lane & 15;
  const int fs = lane & 7;
  const int fc = lane >> 4;
  const int c0 = ((0 + fc) ^ fs) * 8;   // kk = 0
  const int c1 = ((4 + fc) ^ fs) * 8;   // kk = 32
  const int aoff = (wm * 64 + fr) * BK; // within-half A row base
  const int boff = (wn * 32 + fr) * BK; // within-half B row base

  // Prologue: tile0 complete + tile1 minus A-hi (staged at q1 of u=0).
  stage_A_half(Ag, sA0,        0,  0, warp, lane);  // A-lo(0)
  stage_B_half(Bg, sB0,        0,  0, warp, lane);  // B-lo(0)
  stage_B_half(Bg, sB0 + HALF, 0,  1, warp, lane);  // B-hi(0)
  stage_A_half(Ag, sA0 + HALF, 0,  1, warp, lane);  // A-hi(0)
  stage_A_half(Ag, sA1,        BK, 0, warp, lane);  // A-lo(1)
  stage_B_half(Bg, sB1,        BK, 0, warp, lane);  // B-lo(1)
  stage_B_half(Bg, sB1 + HALF, BK, 1, warp, lane);  // B-hi(1)
  asm volatile("s_waitcnt vmcnt(6)" ::: "memory");  // tile0's 8 loads done
  __builtin_amdgcn_s_barrier();
  __builtin_amdgcn_sched_barrier(0);

#pragma unroll 1
  for (int u = 0; u < NT; u += 2) {
    do_tile(sA0, sB0, sA1, Ag, Bg, (u + 1) * BK, (u + 2) * BK,
            (u + 1) < NT, (u + 2) < NT, warp, lane, aoff, boff, c0, c1, acc);
    do_tile(sA1, sB1, sA0, Ag, Bg, (u + 2) * BK, (u + 3) * BK,
            (u + 2) < NT, (u + 3) < NT, warp, lane, aoff, boff, c0, c1, acc);
  }

  // Epilogue: C/D layout col=lane&15, row=(lane>>4)*4+reg
  const int cm = (lane >> 4) * 4;
  const int cn = lane & 15;
#pragma unroll
  for (int j = 0; j < 4; ++j) {
    const int col = n0 + wn * 64 + j * 16 + cn;
    const float bv = bias[col];
#pragma unroll
    for (int i = 0; i < 8; ++i) {
      const int rowb = m0 + wm * 128 + i * 16 + cm;
      float* outp = C + (size_t)rowb * N_DIM + col;
#pragma unroll
      for (int r = 0; r < 4; ++r)
        outp[(size_t)r * N_DIM] = acc[i][j][r] + bv;
    }
  }
}

// -------------------------------------------------------------------------
extern "C" void kernel_launch(void* const* d_in, const int* in_sizes, int n_in,
                              void* d_out, int out_size, void* d_ws, size_t ws_size,
                              hipStream_t stream) {
  const float* x      = (const float*)d_in[0];  // [4,2048,4096] fp32
  const float* weight = (const float*)d_in[1];  // [4096,4096] fp32
  const float* bias   = (const float*)d_in[2];  // [4096] fp32
  float* out          = (float*)d_out;          // [4,2048,4096] fp32

  // Workspace: wq bf16 [N,K] (32 MB) then xb bf16 [M,K] (64 MB)
  bf16* wq = (bf16*)d_ws;
  bf16* xb = (bf16*)((char*)d_ws + (size_t)N_DIM * K_DIM * sizeof(bf16));

  // 1) fake-quant + cast W
  {
    int threads = (N_DIM * K_DIM) / 8;
    quant_w_kernel<<<threads / 256, 256, 0, stream>>>(weight, wq);
  }
  // 2) cast X
  {
    int threads = (M_DIM * K_DIM) / 8;
    cast_x_kernel<<<threads / 256, 256, 0, stream>>>(x, xb);
  }
  // 3) GEMM: 256x256 tiles, 512 threads, 128 KiB dynamic LDS
  {
    constexpr int smem_bytes = 4 * BM * BK * (int)sizeof(bf16);  // 131072
    static bool attr_done = false;
    if (!attr_done) {
      (void)hipFuncSetAttribute((const void*)gemm_bt_kernel,
                                hipFuncAttributeMaxDynamicSharedMemorySize,
                                smem_bytes);
      attr_done = true;
    }
    dim3 grid(N_DIM / BN, M_DIM / BM);  // 16 x 32 = 512 blocks
    gemm_bt_kernel<<<grid, 512, smem_bytes, stream>>>(xb, wq, bias, out);
  }
}